// Round 3
// baseline (20064.317 us; speedup 1.0000x reference)
//
#include <hip/hip_runtime.h>

// Problem constants (from reference)
#define S_TOTAL 19648      // B*N sequential LSTM steps
#define T_CH    12         // independent chains
#define HID     128
#define NTHREADS 1024

// LDS h-tilde buffer layout (per buffer):
//   8 chunks of 20 floats (16 h-values + 4 pad) -> swizzle so each octant's
//   ds_read_b128 base lands on a distinct bank quad (chunk bases mod 32:
//   {0,20,8,28,16,4,24,12} -> the 8 b128 reads cover all 32 banks exactly
//   once -> conflict-free broadcast).
//   ext slots [160..167]: [160..162]=x0..x2, [163]=1.0 (bias lane), [164..167]=0
#define BUFSZ   176
#define EXT_OFF 160

__device__ __forceinline__ int hslot_of(int idx) {
    return ((idx >> 4) * 20) + (idx & 15);
}

// One block per chain (12 blocks), 1024 threads.
// tid = j*8 + o: j = h-index (0..127), o = k-octant (0..7).
// Thread holds W_hh rows {q*128+j} restricted to k in [16o,16o+16) -> 64 regs,
// plus one extended-k weight per gate (x / bias slot) -> 68 weight VGPRs.
//
// waves_per_eu(4,4): PIN occupancy at 4 waves/EU (1 block/CU). R1/R2 showed
// the allocator's occupancy heuristic targets the 64-VGPR tier and spills the
// weight array (R2: VGPR_Count=60, WRITE_SIZE 6.1MB vs 0.94MB output).
// Pinning min=max removes the incentive: allocator may use the full
// 512/4 = 128 VGPRs without spilling.
__global__ __attribute__((amdgpu_flat_work_group_size(NTHREADS, NTHREADS),
                          amdgpu_waves_per_eu(4, 4)))
void lstm_chain(
    const float* __restrict__ x,      // (S,3,12) flat: s*36 + f*12 + t
    const float* __restrict__ W_ih,   // (512,3)
    const float* __restrict__ W_hh,   // (512,128)
    const float* __restrict__ b_ih,   // (512)
    const float* __restrict__ b_hh,   // (512)
    const float* __restrict__ W_lin,  // (128)
    const float* __restrict__ b_lin,  // (1)
    float* __restrict__ out)          // (S,12) flat: s*12 + t
{
    const int t   = blockIdx.x;
    const int tid = threadIdx.x;
    const int j   = tid >> 3;   // h index
    const int o   = tid & 7;    // k octant

    __shared__ __align__(16) float bufs[2 * BUFSZ];

    // ---- load weights into registers (one-time) ----
    float w[4][16];   // gate q, k = 16o+m
    float wt[4];      // extended-k weight (slot 160+o): x-weights / bias / 0
#pragma unroll
    for (int q = 0; q < 4; ++q) {
        const int row = q * HID + j;
        const float* wr = &W_hh[row * HID + 16 * o];
#pragma unroll
        for (int mm = 0; mm < 4; ++mm) {
            float4 v = *(const float4*)&wr[4 * mm];
            w[q][4 * mm + 0] = v.x;
            w[q][4 * mm + 1] = v.y;
            w[q][4 * mm + 2] = v.z;
            w[q][4 * mm + 3] = v.w;
        }
        float tw = 0.0f;
        if (o < 3)       tw = W_ih[row * 3 + o];          // x_o weight
        else if (o == 3) tw = b_ih[row] + b_hh[row];      // bias (slot holds 1.0)
        wt[q] = tw;
    }

    // Wave 1 owns the (deferred-by-one) output dot.
    float wl0 = 0.0f, wl1 = 0.0f;
    const float blin = b_lin[0];
    const int L = tid - 64;   // meaningful for tid in [64,128)
    if (tid >= 64 && tid < 128) { wl0 = W_lin[2 * L]; wl1 = W_lin[2 * L + 1]; }

    const int hslot = hslot_of(j);
    const int chunk = 20 * o;

    // ---- init LDS buffers ----
    if (tid < HID) bufs[hslot_of(tid)] = 0.0f;   // h_{-1} = 0 in buf0
    if (tid == 3) { bufs[EXT_OFF + 3] = 1.0f; bufs[BUFSZ + EXT_OFF + 3] = 1.0f; }
    if (tid >= 4 && tid < 8) { bufs[EXT_OFF + tid] = 0.0f; bufs[BUFSZ + EXT_OFF + tid] = 0.0f; }
    if (tid < 3) bufs[EXT_OFF + tid] = x[tid * 12 + t];   // x for s=0
    float c = 0.0f;
    __syncthreads();

    for (int s = 0; s < S_TOTAL; ++s) {
        float* cur = &bufs[(s & 1) * BUFSZ];          // holds h~_{s-1}
        float* nxt = &bufs[((s & 1) ^ 1) * BUFSZ];    // receives h~_s

        // Prefetch x for step s+1 (3 lanes of wave 0); L2-resident after the
        // first pass (x lines are shared by all 12 blocks).
        float xr = 0.0f;
        if (tid < 3) {
            const int sn = (s + 1 < S_TOTAL) ? (s + 1) : s;
            xr = x[sn * 36 + tid * 12 + t];
        }

        // ---- partial dots: 4 gates x 17 k-elems ----
        const float tail = cur[EXT_OFF + o];
        const float4 h0 = *(const float4*)&cur[chunk + 0];
        const float4 h1 = *(const float4*)&cur[chunk + 4];
        const float4 h2 = *(const float4*)&cur[chunk + 8];
        const float4 h3 = *(const float4*)&cur[chunk + 12];

        float a0 = wt[0] * tail;
        float a1 = wt[1] * tail;
        float a2 = wt[2] * tail;
        float a3 = wt[3] * tail;
#pragma unroll
        for (int q = 0; q < 1; ++q) {}  // (keep structure flat)
        {
            a0 = __builtin_fmaf(h0.x, w[0][0],  a0); a1 = __builtin_fmaf(h0.x, w[1][0],  a1);
            a2 = __builtin_fmaf(h0.x, w[2][0],  a2); a3 = __builtin_fmaf(h0.x, w[3][0],  a3);
            a0 = __builtin_fmaf(h0.y, w[0][1],  a0); a1 = __builtin_fmaf(h0.y, w[1][1],  a1);
            a2 = __builtin_fmaf(h0.y, w[2][1],  a2); a3 = __builtin_fmaf(h0.y, w[3][1],  a3);
            a0 = __builtin_fmaf(h0.z, w[0][2],  a0); a1 = __builtin_fmaf(h0.z, w[1][2],  a1);
            a2 = __builtin_fmaf(h0.z, w[2][2],  a2); a3 = __builtin_fmaf(h0.z, w[3][2],  a3);
            a0 = __builtin_fmaf(h0.w, w[0][3],  a0); a1 = __builtin_fmaf(h0.w, w[1][3],  a1);
            a2 = __builtin_fmaf(h0.w, w[2][3],  a2); a3 = __builtin_fmaf(h0.w, w[3][3],  a3);
            a0 = __builtin_fmaf(h1.x, w[0][4],  a0); a1 = __builtin_fmaf(h1.x, w[1][4],  a1);
            a2 = __builtin_fmaf(h1.x, w[2][4],  a2); a3 = __builtin_fmaf(h1.x, w[3][4],  a3);
            a0 = __builtin_fmaf(h1.y, w[0][5],  a0); a1 = __builtin_fmaf(h1.y, w[1][5],  a1);
            a2 = __builtin_fmaf(h1.y, w[2][5],  a2); a3 = __builtin_fmaf(h1.y, w[3][5],  a3);
            a0 = __builtin_fmaf(h1.z, w[0][6],  a0); a1 = __builtin_fmaf(h1.z, w[1][6],  a1);
            a2 = __builtin_fmaf(h1.z, w[2][6],  a2); a3 = __builtin_fmaf(h1.z, w[3][6],  a3);
            a0 = __builtin_fmaf(h1.w, w[0][7],  a0); a1 = __builtin_fmaf(h1.w, w[1][7],  a1);
            a2 = __builtin_fmaf(h1.w, w[2][7],  a2); a3 = __builtin_fmaf(h1.w, w[3][7],  a3);
            a0 = __builtin_fmaf(h2.x, w[0][8],  a0); a1 = __builtin_fmaf(h2.x, w[1][8],  a1);
            a2 = __builtin_fmaf(h2.x, w[2][8],  a2); a3 = __builtin_fmaf(h2.x, w[3][8],  a3);
            a0 = __builtin_fmaf(h2.y, w[0][9],  a0); a1 = __builtin_fmaf(h2.y, w[1][9],  a1);
            a2 = __builtin_fmaf(h2.y, w[2][9],  a2); a3 = __builtin_fmaf(h2.y, w[3][9],  a3);
            a0 = __builtin_fmaf(h2.z, w[0][10], a0); a1 = __builtin_fmaf(h2.z, w[1][10], a1);
            a2 = __builtin_fmaf(h2.z, w[2][10], a2); a3 = __builtin_fmaf(h2.z, w[3][10], a3);
            a0 = __builtin_fmaf(h2.w, w[0][11], a0); a1 = __builtin_fmaf(h2.w, w[1][11], a1);
            a2 = __builtin_fmaf(h2.w, w[2][11], a2); a3 = __builtin_fmaf(h2.w, w[3][11], a3);
            a0 = __builtin_fmaf(h3.x, w[0][12], a0); a1 = __builtin_fmaf(h3.x, w[1][12], a1);
            a2 = __builtin_fmaf(h3.x, w[2][12], a2); a3 = __builtin_fmaf(h3.x, w[3][12], a3);
            a0 = __builtin_fmaf(h3.y, w[0][13], a0); a1 = __builtin_fmaf(h3.y, w[1][13], a1);
            a2 = __builtin_fmaf(h3.y, w[2][13], a2); a3 = __builtin_fmaf(h3.y, w[3][13], a3);
            a0 = __builtin_fmaf(h3.z, w[0][14], a0); a1 = __builtin_fmaf(h3.z, w[1][14], a1);
            a2 = __builtin_fmaf(h3.z, w[2][14], a2); a3 = __builtin_fmaf(h3.z, w[3][14], a3);
            a0 = __builtin_fmaf(h3.w, w[0][15], a0); a1 = __builtin_fmaf(h3.w, w[1][15], a1);
            a2 = __builtin_fmaf(h3.w, w[2][15], a2); a3 = __builtin_fmaf(h3.w, w[3][15], a3);
        }

        // ---- butterfly across the 8-lane j-group: all lanes get all 4 sums ----
#pragma unroll
        for (int mk = 1; mk <= 4; mk <<= 1) {
            a0 += __shfl_xor(a0, mk, 64);
            a1 += __shfl_xor(a1, mk, 64);
            a2 += __shfl_xor(a2, mk, 64);
            a3 += __shfl_xor(a3, mk, 64);
        }

        // ---- distributed transcendentals (lane-role o&3 does one gate) ----
        const int o2 = o & 3;
        const float arg = (o2 == 0) ? a0 : (o2 == 1) ? a1 : (o2 == 2) ? a2 : a3;
        const float sc  = (o2 == 2) ? -2.0f : -1.0f;
        const float e   = __expf(arg * sc);
        const float r   = __builtin_amdgcn_rcpf(1.0f + e);
        const float val = (o2 == 2) ? __builtin_fmaf(2.0f, r, -1.0f) : r;  // tanh vs sigmoid
        // reassemble on role-0 lanes: val=zi, vf=zf, vg=zg, vo=zo
        const float vf = __shfl_xor(val, 1, 64);
        const float vg = __shfl_xor(val, 2, 64);
        const float vo = __shfl_xor(val, 3, 64);
        const float cn = __builtin_fmaf(vf, c, val * vg);
        c = cn;                                   // meaningful on o==0 (and o==4) lanes
        const float e2 = __expf(-2.0f * cn);
        const float th = __builtin_fmaf(2.0f, __builtin_amdgcn_rcpf(1.0f + e2), -1.0f);
        const float hn = vo * th;
        if (o == 0) nxt[hslot] = hn;              // publish h_s
        if (tid < 3) nxt[EXT_OFF + tid] = xr;     // publish x_{s+1}

        // ---- wave 1: out[s-1] = h_{s-1} . W_lin + b_lin (cur still h_{s-1}) ----
        if (tid >= 64 && tid < 128) {
            const int p0 = 2 * L;
            const int sl = hslot_of(p0);          // p0 even -> sl even, 8B-aligned
            const float2 hp = *(const float2*)&cur[sl];
            float po = __builtin_fmaf(hp.x, wl0, hp.y * wl1);
#pragma unroll
            for (int mk = 32; mk >= 1; mk >>= 1) po += __shfl_xor(po, mk, 64);
            if (tid == 64 && s > 0) out[(s - 1) * T_CH + t] = po + blin;
        }

        __syncthreads();   // h_s / x_{s+1} visible; cur free for overwrite next step
    }

    // ---- epilogue: out[S-1] ----
    {
        const float* fin = &bufs[(S_TOTAL & 1) * BUFSZ];
        if (tid >= 64 && tid < 128) {
            const int p0 = 2 * L;
            const int sl = hslot_of(p0);
            const float2 hp = *(const float2*)&fin[sl];
            float po = __builtin_fmaf(hp.x, wl0, hp.y * wl1);
#pragma unroll
            for (int mk = 32; mk >= 1; mk >>= 1) po += __shfl_xor(po, mk, 64);
            if (tid == 64) out[(S_TOTAL - 1) * T_CH + t] = po + blin;
        }
    }
}

extern "C" void kernel_launch(void* const* d_in, const int* in_sizes, int n_in,
                              void* d_out, int out_size, void* d_ws, size_t ws_size,
                              hipStream_t stream) {
    const float* x     = (const float*)d_in[0];
    const float* W_ih  = (const float*)d_in[1];
    const float* W_hh  = (const float*)d_in[2];
    const float* b_ih  = (const float*)d_in[3];
    const float* b_hh  = (const float*)d_in[4];
    const float* W_lin = (const float*)d_in[5];
    const float* b_lin = (const float*)d_in[6];
    float* out = (float*)d_out;

    hipLaunchKernelGGL(lstm_chain, dim3(T_CH), dim3(NTHREADS), 0, stream,
                       x, W_ih, W_hh, b_ih, b_hh, W_lin, b_lin, out);
}

// Round 4
// 19868.143 us; speedup vs baseline: 1.0099x; 1.0099x over previous
//
#include <hip/hip_runtime.h>

// Problem constants (from reference)
#define S_TOTAL 19648      // B*N sequential LSTM steps
#define T_CH    12         // independent chains
#define HID     128
#define NTHREADS 1024

// LDS h-tilde buffer layout (per buffer):
//   8 chunks of 20 floats (16 h-values + 4 pad) -> swizzle so each octant's
//   ds_read_b128 base lands on a distinct bank quad (chunk bases mod 32:
//   {0,20,8,28,16,4,24,12} -> the 8 b128 reads cover all 32 banks exactly
//   once -> conflict-free broadcast).
//   ext slots [160..167]: [160..162]=x0..x2, [163]=1.0 (bias lane), [164..167]=0
#define BUFSZ   176
#define EXT_OFF 160

__device__ __forceinline__ int hslot_of(int idx) {
    return ((idx >> 4) * 20) + (idx & 15);
}

// One block per chain (12 blocks), 1024 threads.
// tid = j*8 + o: j = h-index (0..127), o = k-octant (0..7).
// Thread holds W_hh rows {q*128+j} restricted to k in [16o,16o+16) -> 64 regs,
// plus one extended-k weight per gate (x / bias slot) -> 68 weight VGPRs.
//
// REGISTER-BUDGET NOTE (R1-R3 evidence): HIP __launch_bounds__ 2nd arg acts
// as CUDA min-BLOCKS-per-CU here:
//   (512,2) -> 16 waves/CU -> budget 128 (observed VGPR=128)
//   (1024,4)-> 32 waves/CU -> budget 64  (observed VGPR=60, spilled weights)
// So (1024,1) -> 16 waves/CU -> 4 waves/EU -> 128 VGPR budget, which fits
// this kernel's ~105 live VGPRs with no spill.
__global__ __launch_bounds__(NTHREADS, 1) void lstm_chain(
    const float* __restrict__ x,      // (S,3,12) flat: s*36 + f*12 + t
    const float* __restrict__ W_ih,   // (512,3)
    const float* __restrict__ W_hh,   // (512,128)
    const float* __restrict__ b_ih,   // (512)
    const float* __restrict__ b_hh,   // (512)
    const float* __restrict__ W_lin,  // (128)
    const float* __restrict__ b_lin,  // (1)
    float* __restrict__ out)          // (S,12) flat: s*12 + t
{
    const int t   = blockIdx.x;
    const int tid = threadIdx.x;
    const int j   = tid >> 3;   // h index
    const int o   = tid & 7;    // k octant

    __shared__ __align__(16) float bufs[2 * BUFSZ];

    // ---- load weights into registers (one-time) ----
    float w[4][16];   // gate q, k = 16o+m
    float wt[4];      // extended-k weight (slot 160+o): x-weights / bias / 0
#pragma unroll
    for (int q = 0; q < 4; ++q) {
        const int row = q * HID + j;
        const float* wr = &W_hh[row * HID + 16 * o];
#pragma unroll
        for (int mm = 0; mm < 4; ++mm) {
            float4 v = *(const float4*)&wr[4 * mm];
            w[q][4 * mm + 0] = v.x;
            w[q][4 * mm + 1] = v.y;
            w[q][4 * mm + 2] = v.z;
            w[q][4 * mm + 3] = v.w;
        }
        float tw = 0.0f;
        if (o < 3)       tw = W_ih[row * 3 + o];          // x_o weight
        else if (o == 3) tw = b_ih[row] + b_hh[row];      // bias (slot holds 1.0)
        wt[q] = tw;
    }

    // Wave 1 owns the (deferred-by-one) output dot.
    float wl0 = 0.0f, wl1 = 0.0f;
    const float blin = b_lin[0];
    const int L = tid - 64;   // meaningful for tid in [64,128)
    if (tid >= 64 && tid < 128) { wl0 = W_lin[2 * L]; wl1 = W_lin[2 * L + 1]; }

    const int hslot = hslot_of(j);
    const int chunk = 20 * o;

    // ---- init LDS buffers ----
    if (tid < HID) bufs[hslot_of(tid)] = 0.0f;   // h_{-1} = 0 in buf0
    if (tid == 3) { bufs[EXT_OFF + 3] = 1.0f; bufs[BUFSZ + EXT_OFF + 3] = 1.0f; }
    if (tid >= 4 && tid < 8) { bufs[EXT_OFF + tid] = 0.0f; bufs[BUFSZ + EXT_OFF + tid] = 0.0f; }
    if (tid < 3) bufs[EXT_OFF + tid] = x[tid * 12 + t];   // x for s=0
    float c = 0.0f;
    __syncthreads();

    for (int s = 0; s < S_TOTAL; ++s) {
        float* cur = &bufs[(s & 1) * BUFSZ];          // holds h~_{s-1}
        float* nxt = &bufs[((s & 1) ^ 1) * BUFSZ];    // receives h~_s

        // Prefetch x for step s+1 (3 lanes of wave 0); L2-resident after the
        // first pass (x lines are shared by all 12 blocks).
        float xr = 0.0f;
        if (tid < 3) {
            const int sn = (s + 1 < S_TOTAL) ? (s + 1) : s;
            xr = x[sn * 36 + tid * 12 + t];
        }

        // ---- partial dots: 4 gates x 17 k-elems ----
        const float tail = cur[EXT_OFF + o];
        const float4 h0 = *(const float4*)&cur[chunk + 0];
        const float4 h1 = *(const float4*)&cur[chunk + 4];
        const float4 h2 = *(const float4*)&cur[chunk + 8];
        const float4 h3 = *(const float4*)&cur[chunk + 12];

        float a0 = wt[0] * tail;
        float a1 = wt[1] * tail;
        float a2 = wt[2] * tail;
        float a3 = wt[3] * tail;
        {
            a0 = __builtin_fmaf(h0.x, w[0][0],  a0); a1 = __builtin_fmaf(h0.x, w[1][0],  a1);
            a2 = __builtin_fmaf(h0.x, w[2][0],  a2); a3 = __builtin_fmaf(h0.x, w[3][0],  a3);
            a0 = __builtin_fmaf(h0.y, w[0][1],  a0); a1 = __builtin_fmaf(h0.y, w[1][1],  a1);
            a2 = __builtin_fmaf(h0.y, w[2][1],  a2); a3 = __builtin_fmaf(h0.y, w[3][1],  a3);
            a0 = __builtin_fmaf(h0.z, w[0][2],  a0); a1 = __builtin_fmaf(h0.z, w[1][2],  a1);
            a2 = __builtin_fmaf(h0.z, w[2][2],  a2); a3 = __builtin_fmaf(h0.z, w[3][2],  a3);
            a0 = __builtin_fmaf(h0.w, w[0][3],  a0); a1 = __builtin_fmaf(h0.w, w[1][3],  a1);
            a2 = __builtin_fmaf(h0.w, w[2][3],  a2); a3 = __builtin_fmaf(h0.w, w[3][3],  a3);
            a0 = __builtin_fmaf(h1.x, w[0][4],  a0); a1 = __builtin_fmaf(h1.x, w[1][4],  a1);
            a2 = __builtin_fmaf(h1.x, w[2][4],  a2); a3 = __builtin_fmaf(h1.x, w[3][4],  a3);
            a0 = __builtin_fmaf(h1.y, w[0][5],  a0); a1 = __builtin_fmaf(h1.y, w[1][5],  a1);
            a2 = __builtin_fmaf(h1.y, w[2][5],  a2); a3 = __builtin_fmaf(h1.y, w[3][5],  a3);
            a0 = __builtin_fmaf(h1.z, w[0][6],  a0); a1 = __builtin_fmaf(h1.z, w[1][6],  a1);
            a2 = __builtin_fmaf(h1.z, w[2][6],  a2); a3 = __builtin_fmaf(h1.z, w[3][6],  a3);
            a0 = __builtin_fmaf(h1.w, w[0][7],  a0); a1 = __builtin_fmaf(h1.w, w[1][7],  a1);
            a2 = __builtin_fmaf(h1.w, w[2][7],  a2); a3 = __builtin_fmaf(h1.w, w[3][7],  a3);
            a0 = __builtin_fmaf(h2.x, w[0][8],  a0); a1 = __builtin_fmaf(h2.x, w[1][8],  a1);
            a2 = __builtin_fmaf(h2.x, w[2][8],  a2); a3 = __builtin_fmaf(h2.x, w[3][8],  a3);
            a0 = __builtin_fmaf(h2.y, w[0][9],  a0); a1 = __builtin_fmaf(h2.y, w[1][9],  a1);
            a2 = __builtin_fmaf(h2.y, w[2][9],  a2); a3 = __builtin_fmaf(h2.y, w[3][9],  a3);
            a0 = __builtin_fmaf(h2.z, w[0][10], a0); a1 = __builtin_fmaf(h2.z, w[1][10], a1);
            a2 = __builtin_fmaf(h2.z, w[2][10], a2); a3 = __builtin_fmaf(h2.z, w[3][10], a3);
            a0 = __builtin_fmaf(h2.w, w[0][11], a0); a1 = __builtin_fmaf(h2.w, w[1][11], a1);
            a2 = __builtin_fmaf(h2.w, w[2][11], a2); a3 = __builtin_fmaf(h2.w, w[3][11], a3);
            a0 = __builtin_fmaf(h3.x, w[0][12], a0); a1 = __builtin_fmaf(h3.x, w[1][12], a1);
            a2 = __builtin_fmaf(h3.x, w[2][12], a2); a3 = __builtin_fmaf(h3.x, w[3][12], a3);
            a0 = __builtin_fmaf(h3.y, w[0][13], a0); a1 = __builtin_fmaf(h3.y, w[1][13], a1);
            a2 = __builtin_fmaf(h3.y, w[2][13], a2); a3 = __builtin_fmaf(h3.y, w[3][13], a3);
            a0 = __builtin_fmaf(h3.z, w[0][14], a0); a1 = __builtin_fmaf(h3.z, w[1][14], a1);
            a2 = __builtin_fmaf(h3.z, w[2][14], a2); a3 = __builtin_fmaf(h3.z, w[3][14], a3);
            a0 = __builtin_fmaf(h3.w, w[0][15], a0); a1 = __builtin_fmaf(h3.w, w[1][15], a1);
            a2 = __builtin_fmaf(h3.w, w[2][15], a2); a3 = __builtin_fmaf(h3.w, w[3][15], a3);
        }

        // ---- butterfly across the 8-lane j-group: all lanes get all 4 sums ----
#pragma unroll
        for (int mk = 1; mk <= 4; mk <<= 1) {
            a0 += __shfl_xor(a0, mk, 64);
            a1 += __shfl_xor(a1, mk, 64);
            a2 += __shfl_xor(a2, mk, 64);
            a3 += __shfl_xor(a3, mk, 64);
        }

        // ---- distributed transcendentals (lane-role o&3 does one gate) ----
        const int o2 = o & 3;
        const float arg = (o2 == 0) ? a0 : (o2 == 1) ? a1 : (o2 == 2) ? a2 : a3;
        const float sc  = (o2 == 2) ? -2.0f : -1.0f;
        const float e   = __expf(arg * sc);
        const float r   = __builtin_amdgcn_rcpf(1.0f + e);
        const float val = (o2 == 2) ? __builtin_fmaf(2.0f, r, -1.0f) : r;  // tanh vs sigmoid
        // reassemble on role-0 lanes: val=zi, vf=zf, vg=zg, vo=zo
        const float vf = __shfl_xor(val, 1, 64);
        const float vg = __shfl_xor(val, 2, 64);
        const float vo = __shfl_xor(val, 3, 64);
        const float cn = __builtin_fmaf(vf, c, val * vg);
        c = cn;                                   // meaningful on o==0 (and o==4) lanes
        const float e2 = __expf(-2.0f * cn);
        const float th = __builtin_fmaf(2.0f, __builtin_amdgcn_rcpf(1.0f + e2), -1.0f);
        const float hn = vo * th;
        if (o == 0) nxt[hslot] = hn;              // publish h_s
        if (tid < 3) nxt[EXT_OFF + tid] = xr;     // publish x_{s+1}

        // ---- wave 1: out[s-1] = h_{s-1} . W_lin + b_lin (cur still h_{s-1}) ----
        if (tid >= 64 && tid < 128) {
            const int p0 = 2 * L;
            const int sl = hslot_of(p0);          // p0 even -> sl even, 8B-aligned
            const float2 hp = *(const float2*)&cur[sl];
            float po = __builtin_fmaf(hp.x, wl0, hp.y * wl1);
#pragma unroll
            for (int mk = 32; mk >= 1; mk >>= 1) po += __shfl_xor(po, mk, 64);
            if (tid == 64 && s > 0) out[(s - 1) * T_CH + t] = po + blin;
        }

        __syncthreads();   // h_s / x_{s+1} visible; cur free for overwrite next step
    }

    // ---- epilogue: out[S-1] ----
    {
        const float* fin = &bufs[(S_TOTAL & 1) * BUFSZ];
        if (tid >= 64 && tid < 128) {
            const int p0 = 2 * L;
            const int sl = hslot_of(p0);
            const float2 hp = *(const float2*)&fin[sl];
            float po = __builtin_fmaf(hp.x, wl0, hp.y * wl1);
#pragma unroll
            for (int mk = 32; mk >= 1; mk >>= 1) po += __shfl_xor(po, mk, 64);
            if (tid == 64) out[(S_TOTAL - 1) * T_CH + t] = po + blin;
        }
    }
}

extern "C" void kernel_launch(void* const* d_in, const int* in_sizes, int n_in,
                              void* d_out, int out_size, void* d_ws, size_t ws_size,
                              hipStream_t stream) {
    const float* x     = (const float*)d_in[0];
    const float* W_ih  = (const float*)d_in[1];
    const float* W_hh  = (const float*)d_in[2];
    const float* b_ih  = (const float*)d_in[3];
    const float* b_hh  = (const float*)d_in[4];
    const float* W_lin = (const float*)d_in[5];
    const float* b_lin = (const float*)d_in[6];
    float* out = (float*)d_out;

    hipLaunchKernelGGL(lstm_chain, dim3(T_CH), dim3(NTHREADS), 0, stream,
                       x, W_ih, W_hh, b_ih, b_hh, W_lin, b_lin, out);
}

// Round 5
// 19227.943 us; speedup vs baseline: 1.0435x; 1.0333x over previous
//
#include <hip/hip_runtime.h>

// Problem constants (from reference)
#define S_TOTAL 19648      // B*N sequential LSTM steps
#define T_CH    12         // independent chains
#define HID     128
#define NTHREADS 1024

typedef _Float16 half2_t __attribute__((ext_vector_type(2)));

// v_dot2_f32_f16: d = a.x*b.x + a.y*b.y + c  (fp32 accumulate, full-rate VOP3P)
__device__ __forceinline__ float fdot2(half2_t a, half2_t b, float c) {
    return __builtin_amdgcn_fdot2(a, b, c, false);
}

// ---------------------------------------------------------------------------
// ALLOCATOR EVIDENCE (R1-R4): for 1024-thread blocks the backend pins the
// VGPR budget at 64 (8 waves/EU) no matter what launch_bounds /
// amdgpu_waves_per_eu say (observed VGPR_Count=60 in R2/R3/R4 with spill
// WRITE_SIZE ~6MB). A 64-reg fp32 weight layout cannot fit. Fix: fp16-packed
// weights + v_dot2_f32_f16 -> 36 weight VGPRs, ~60 total live. No spill.
//
// Decomposition: one block per chain (12 blocks), 1024 threads.
// tid = j*8 + o: j = h-index (0..127), o = k-octant (0..7, 16 k each).
// Thread holds the 4 gate rows {q*128+j} restricted to k in [16o,16o+16),
// packed as 8 half2 per gate (32 VGPRs) + 1 fp32 tail weight per gate
// (x-weight / fused bias via ext slot holding 1.0).
//
// h is stored in LDS as fp16, 8 chunks of 16 values + 8 pad (stride 24 fp16
// = 48B): chunk base banks 12o mod 32 = {0,12,24,4,16,28,8,20} all distinct
// -> the 8 broadcast ds_read_b128 are conflict-free.
// ---------------------------------------------------------------------------
#define CH_STRIDE 24            // fp16 units per chunk (16 used + 8 pad)

__global__ __launch_bounds__(NTHREADS) void lstm_chain(
    const float* __restrict__ x,      // (S,3,12) flat: s*36 + f*12 + t
    const float* __restrict__ W_ih,   // (512,3)
    const float* __restrict__ W_hh,   // (512,128)
    const float* __restrict__ b_ih,   // (512)
    const float* __restrict__ b_hh,   // (512)
    const float* __restrict__ W_lin,  // (128)
    const float* __restrict__ b_lin,  // (1)
    float* __restrict__ out)          // (S,12) flat: s*12 + t
{
    const int t   = blockIdx.x;
    const int tid = threadIdx.x;
    const int j   = tid >> 3;   // h index
    const int o   = tid & 7;    // k octant

    __shared__ __align__(16) _Float16 hbuf[2][8 * CH_STRIDE];  // 2 x 384B
    __shared__ float extb[2][8];  // [0..2]=x0..x2, [3]=1.0 (bias), [4..7]=0

    // ---- pack weights into registers (one-time) ----
    half2_t w2[4][8];   // gate q, k-pair m (k = 16o + 2m, 16o + 2m + 1)
    float   wt[4];      // tail weight vs ext slot o: x / bias / 0
#pragma unroll
    for (int q = 0; q < 4; ++q) {
        const int row = q * HID + j;
        const float* wr = &W_hh[row * HID + 16 * o];
#pragma unroll
        for (int m = 0; m < 8; ++m) {
            half2_t p;
            p.x = (_Float16)wr[2 * m];
            p.y = (_Float16)wr[2 * m + 1];
            w2[q][m] = p;
        }
        float tw = 0.0f;
        if (o < 3)       tw = W_ih[row * 3 + o];
        else if (o == 3) tw = b_ih[row] + b_hh[row];
        wt[q] = tw;
    }

    // Wave 1 owns the (deferred-by-one) output dot: lane L holds
    // W_lin[2L], W_lin[2L+1] packed fp16.
    half2_t wl2; wl2.x = (_Float16)0.0f; wl2.y = (_Float16)0.0f;
    const float blin = b_lin[0];
    const int L = tid - 64;    // meaningful for tid in [64,128)
    if (tid >= 64 && tid < 128) {
        wl2.x = (_Float16)W_lin[2 * L];
        wl2.y = (_Float16)W_lin[2 * L + 1];
    }

    // ---- init LDS ----
    if (tid < HID) hbuf[0][(tid >> 4) * CH_STRIDE + (tid & 15)] = (_Float16)0.0f;
    if (tid == 3) { extb[0][3] = 1.0f; extb[1][3] = 1.0f; }
    if (tid >= 4 && tid < 8) { extb[0][tid] = 0.0f; extb[1][tid] = 0.0f; }
    if (tid < 3) extb[0][tid] = x[tid * 12 + t];   // x for s=0
    float c = 0.0f;
    __syncthreads();

    for (int s = 0; s < S_TOTAL; ++s) {
        const int pb = s & 1;
        const _Float16* hc = &hbuf[pb][CH_STRIDE * o];

        // Prefetch x for step s+1 (3 lanes); L2-resident, vmcnt hidden.
        float xr = 0.0f;
        if (tid < 3) {
            const int sn = (s + 1 < S_TOTAL) ? (s + 1) : s;
            xr = x[sn * 36 + tid * 12 + t];
        }

        // ---- broadcast-read this octant's 16 h values (2x ds_read_b128) ----
        const float4 f0 = *(const float4*)&hc[0];   // 8 fp16
        const float4 f1 = *(const float4*)&hc[8];   // 8 fp16
        const half2_t p0 = __builtin_bit_cast(half2_t, f0.x);
        const half2_t p1 = __builtin_bit_cast(half2_t, f0.y);
        const half2_t p2 = __builtin_bit_cast(half2_t, f0.z);
        const half2_t p3 = __builtin_bit_cast(half2_t, f0.w);
        const half2_t p4 = __builtin_bit_cast(half2_t, f1.x);
        const half2_t p5 = __builtin_bit_cast(half2_t, f1.y);
        const half2_t p6 = __builtin_bit_cast(half2_t, f1.z);
        const half2_t p7 = __builtin_bit_cast(half2_t, f1.w);
        const float tail = extb[pb][o];             // same-addr broadcast per o

        // ---- partial dots: 4 gates x (1 tail fma + 8 dot2) ----
        float a0 = wt[0] * tail;
        float a1 = wt[1] * tail;
        float a2 = wt[2] * tail;
        float a3 = wt[3] * tail;
        a0 = fdot2(p0, w2[0][0], a0); a1 = fdot2(p0, w2[1][0], a1);
        a2 = fdot2(p0, w2[2][0], a2); a3 = fdot2(p0, w2[3][0], a3);
        a0 = fdot2(p1, w2[0][1], a0); a1 = fdot2(p1, w2[1][1], a1);
        a2 = fdot2(p1, w2[2][1], a2); a3 = fdot2(p1, w2[3][1], a3);
        a0 = fdot2(p2, w2[0][2], a0); a1 = fdot2(p2, w2[1][2], a1);
        a2 = fdot2(p2, w2[2][2], a2); a3 = fdot2(p2, w2[3][2], a3);
        a0 = fdot2(p3, w2[0][3], a0); a1 = fdot2(p3, w2[1][3], a1);
        a2 = fdot2(p3, w2[2][3], a2); a3 = fdot2(p3, w2[3][3], a3);
        a0 = fdot2(p4, w2[0][4], a0); a1 = fdot2(p4, w2[1][4], a1);
        a2 = fdot2(p4, w2[2][4], a2); a3 = fdot2(p4, w2[3][4], a3);
        a0 = fdot2(p5, w2[0][5], a0); a1 = fdot2(p5, w2[1][5], a1);
        a2 = fdot2(p5, w2[2][5], a2); a3 = fdot2(p5, w2[3][5], a3);
        a0 = fdot2(p6, w2[0][6], a0); a1 = fdot2(p6, w2[1][6], a1);
        a2 = fdot2(p6, w2[2][6], a2); a3 = fdot2(p6, w2[3][6], a3);
        a0 = fdot2(p7, w2[0][7], a0); a1 = fdot2(p7, w2[1][7], a1);
        a2 = fdot2(p7, w2[2][7], a2); a3 = fdot2(p7, w2[3][7], a3);

        // ---- butterfly across the 8-lane j-group ----
#pragma unroll
        for (int mk = 1; mk <= 4; mk <<= 1) {
            a0 += __shfl_xor(a0, mk, 64);
            a1 += __shfl_xor(a1, mk, 64);
            a2 += __shfl_xor(a2, mk, 64);
            a3 += __shfl_xor(a3, mk, 64);
        }

        // ---- distributed transcendentals (lane-role o&3 does one gate) ----
        const int o2 = o & 3;
        const float arg = (o2 == 0) ? a0 : (o2 == 1) ? a1 : (o2 == 2) ? a2 : a3;
        const float sc  = (o2 == 2) ? -2.0f : -1.0f;
        const float e   = __expf(arg * sc);
        const float r   = __builtin_amdgcn_rcpf(1.0f + e);
        const float val = (o2 == 2) ? __builtin_fmaf(2.0f, r, -1.0f) : r;
        const float vf = __shfl_xor(val, 1, 64);
        const float vg = __shfl_xor(val, 2, 64);
        const float vo = __shfl_xor(val, 3, 64);
        const float cn = __builtin_fmaf(vf, c, val * vg);
        c = cn;                                    // valid on o==0 / o==4 lanes
        const float e2 = __expf(-2.0f * cn);
        const float th = __builtin_fmaf(2.0f, __builtin_amdgcn_rcpf(1.0f + e2), -1.0f);
        const float hn = vo * th;
        if (o == 0)                                // publish h_s (fp16, 2B write)
            hbuf[pb ^ 1][(j >> 4) * CH_STRIDE + (j & 15)] = (_Float16)hn;
        if (tid < 3) extb[pb ^ 1][tid] = xr;       // publish x_{s+1}

        // ---- wave 1: out[s-1] = h_{s-1} . W_lin + b_lin ----
        if (tid >= 64 && tid < 128) {
            const half2_t hp = *(const half2_t*)&hbuf[pb][(L >> 3) * CH_STRIDE + ((L & 7) << 1)];
            float po = fdot2(hp, wl2, 0.0f);
#pragma unroll
            for (int mk = 32; mk >= 1; mk >>= 1) po += __shfl_xor(po, mk, 64);
            if (tid == 64 && s > 0) out[(s - 1) * T_CH + t] = po + blin;
        }

        __syncthreads();   // h_s / x_{s+1} visible; cur buffer free next step
    }

    // ---- epilogue: out[S-1] ----
    if (tid >= 64 && tid < 128) {
        const int fb = S_TOTAL & 1;
        const half2_t hp = *(const half2_t*)&hbuf[fb][(L >> 3) * CH_STRIDE + ((L & 7) << 1)];
        float po = fdot2(hp, wl2, 0.0f);
#pragma unroll
        for (int mk = 32; mk >= 1; mk >>= 1) po += __shfl_xor(po, mk, 64);
        if (tid == 64) out[(S_TOTAL - 1) * T_CH + t] = po + blin;
    }
}

extern "C" void kernel_launch(void* const* d_in, const int* in_sizes, int n_in,
                              void* d_out, int out_size, void* d_ws, size_t ws_size,
                              hipStream_t stream) {
    const float* x     = (const float*)d_in[0];
    const float* W_ih  = (const float*)d_in[1];
    const float* W_hh  = (const float*)d_in[2];
    const float* b_ih  = (const float*)d_in[3];
    const float* b_hh  = (const float*)d_in[4];
    const float* W_lin = (const float*)d_in[5];
    const float* b_lin = (const float*)d_in[6];
    float* out = (float*)d_out;

    hipLaunchKernelGGL(lstm_chain, dim3(T_CH), dim3(NTHREADS), 0, stream,
                       x, W_ih, W_hh, b_ih, b_hh, W_lin, b_lin, out);
}

// Round 7
// 18937.718 us; speedup vs baseline: 1.0595x; 1.0153x over previous
//
#include <hip/hip_runtime.h>

// Problem constants
#define S_TOTAL 19648      // B*N sequential LSTM steps
#define T_CH    12         // chains = MFMA N dimension (padded to 16)
#define HID     128
#define NT      512        // 8 waves, one block total (grid = 1)

typedef _Float16 half8 __attribute__((ext_vector_type(8)));
typedef _Float16 half2v __attribute__((ext_vector_type(2)));
typedef float f4 __attribute__((ext_vector_type(4)));

__device__ __forceinline__ float fast_sigmoid(float v) {
    return __builtin_amdgcn_rcpf(1.0f + __expf(-v));
}
__device__ __forceinline__ float fast_tanh(float v) {
    return 2.0f * __builtin_amdgcn_rcpf(1.0f + __expf(-2.0f * v)) - 1.0f;
}
__device__ __forceinline__ float fdot2(half2v a, half2v b, float c) {
    return __builtin_amdgcn_fdot2(a, b, c, false);
}

// ---------------------------------------------------------------------------
// R5 post-mortem: the 8-lane shuffle butterfly saturated the per-CU DS pipe
// (~290 ds ops/step ~ 2300 cyc — matches measured step time; halving VALU
// work changed nothing). This kernel replaces it with MFMA over all 12
// chains at once: Z(512x12) = W(512x132) @ [h;x0,x1,x2,1](132x12).
//
// One block, 8 waves. Wave w owns j-tile [16w,16w+16) for ALL FOUR gates
// (M-tiles at rows q*128+16w, q=0..3) -> i,f,g,o for a given (j,chain) land
// in the SAME lane (C-layout: col=lane&15=chain, row=(lane>>4)*4+reg=j) ->
// c/h update fully in-lane, zero shuffles in the recurrence.
// K = 4 tiles of 32 (h as fp16) + 1 ext K=32 tile (x0,x1,x2,bias in k=0..3,
// rest zero). A/B fragment layout (16x16x32): row/col = lane&15,
// k = (lane>>4)*8 + elem.
// h redistribution C->B layout goes through an LDS buffer stored in exact
// B-fragment order: two ds_write_b32-pairs/lane, 4 ds_read_b128/wave.
// Double-buffered, ONE barrier per step.
// ---------------------------------------------------------------------------
__global__ __launch_bounds__(NT, 2) void lstm_mfma(
    const float* __restrict__ x,      // (S,3,12): s*36 + f*12 + t
    const float* __restrict__ W_ih,   // (512,3)
    const float* __restrict__ W_hh,   // (512,128)
    const float* __restrict__ b_ih,   // (512)
    const float* __restrict__ b_hh,   // (512)
    const float* __restrict__ W_lin,  // (128)
    const float* __restrict__ b_lin,  // (1)
    float* __restrict__ out)          // (S,12): s*12 + t
{
    const int tid = threadIdx.x;
    const int w   = tid >> 6;    // wave 0..7  -> j-tile base 16w
    const int l   = tid & 63;
    const int n   = l & 15;      // chain (B/C/D col); for A, l&15 is row m
    const int qk  = l >> 4;      // k-quad / row-quad

    // hfrag[buf][kt][lane][8 fp16]: element [kt][g*16+n][e] = h[kt*32+g*8+e][n]
    __shared__ __align__(16) _Float16 hfrag[2][4][64][8];   // 8 KB
    __shared__ float pout[2][16][8];                        // partial out sums

    // ---- load A fragments (W_hh -> fp16, once) ----
    // A-tile (gate q): row m = q*128 + 16w + (l&15); k = kt*32 + qk*8 + e
    half8 A[4][4];
    half8 Aext[4];
#pragma unroll
    for (int q = 0; q < 4; ++q) {
        const int row = q * HID + 16 * w + (l & 15);
#pragma unroll
        for (int kt = 0; kt < 4; ++kt) {
            const float* src = &W_hh[row * HID + kt * 32 + qk * 8];
            half8 a;
#pragma unroll
            for (int e = 0; e < 8; ++e) a[e] = (_Float16)src[e];
            A[q][kt] = a;
        }
        half8 ae = {};   // ext tile: k=0..3 live on qk==0 lanes only
        if (qk == 0) {
            ae[0] = (_Float16)W_ih[row * 3 + 0];
            ae[1] = (_Float16)W_ih[row * 3 + 1];
            ae[2] = (_Float16)W_ih[row * 3 + 2];
            ae[3] = (_Float16)(b_ih[row] + b_hh[row]);
        }
        Aext[q] = ae;
    }

    // W_lin pairs for this lane's 4 output rows j0..j0+3 (j0 = 16w + 4qk)
    const int j0 = 16 * w + 4 * qk;
    half2v wl01, wl23;
    wl01[0] = (_Float16)W_lin[j0];     wl01[1] = (_Float16)W_lin[j0 + 1];
    wl23[0] = (_Float16)W_lin[j0 + 2]; wl23[1] = (_Float16)W_lin[j0 + 3];
    const float blin = b_lin[0];

    // Persistent B-ext: k=3 slot = 1.0 (bias) on qk==0 lanes, chains 0..11
    half8 Bext = {};
    if (qk == 0 && n < T_CH) Bext[3] = (_Float16)1.0f;

    // ---- zero LDS ----
    ((uint4*)hfrag)[tid] = make_uint4(0, 0, 0, 0);   // 512 * 16B = 8 KB
    if (tid < 256) ((float*)pout)[tid] = 0.0f;

    // cell state for this lane's 4 (j, chain=n) cells
    float c0 = 0.f, c1 = 0.f, c2 = 0.f, c3 = 0.f;

    // x prefetch for s=0
    float xf0 = 0.f, xf1 = 0.f, xf2 = 0.f;
    if (qk == 0 && n < T_CH) { xf0 = x[n]; xf1 = x[12 + n]; xf2 = x[24 + n]; }

    __syncthreads();

    for (int s = 0; s < S_TOTAL; ++s) {
        const int p = s & 1;

        // Bext <- x_s (k=0..2 slots)
        if (qk == 0 && n < T_CH) {
            Bext[0] = (_Float16)xf0;
            Bext[1] = (_Float16)xf1;
            Bext[2] = (_Float16)xf2;
        }
        // prefetch x for s+1 (L2-resident; vmcnt drain hidden behind step)
        {
            const int sn = (s + 1 < S_TOTAL) ? (s + 1) : s;
            if (qk == 0 && n < T_CH) {
                xf0 = x[sn * 36 + n];
                xf1 = x[sn * 36 + 12 + n];
                xf2 = x[sn * 36 + 24 + n];
            }
        }

        // ---- read B fragments (h_{s-1}) : 4x ds_read_b128, broadcast in wave ----
        const half8 B0 = *(const half8*)&hfrag[p][0][l][0];
        const half8 B1 = *(const half8*)&hfrag[p][1][l][0];
        const half8 B2 = *(const half8*)&hfrag[p][2][l][0];
        const half8 B3 = *(const half8*)&hfrag[p][3][l][0];

        // ---- Z = Wext.[x;1] + Whh.h  (per wave: 4 gate accum tiles) ----
        const f4 z = {0.f, 0.f, 0.f, 0.f};
        f4 ac0 = __builtin_amdgcn_mfma_f32_16x16x32_f16(Aext[0], Bext, z, 0, 0, 0);
        f4 ac1 = __builtin_amdgcn_mfma_f32_16x16x32_f16(Aext[1], Bext, z, 0, 0, 0);
        f4 ac2 = __builtin_amdgcn_mfma_f32_16x16x32_f16(Aext[2], Bext, z, 0, 0, 0);
        f4 ac3 = __builtin_amdgcn_mfma_f32_16x16x32_f16(Aext[3], Bext, z, 0, 0, 0);
#pragma unroll
        for (int kt = 0; kt < 4; ++kt) {
            const half8 B = (kt == 0) ? B0 : (kt == 1) ? B1 : (kt == 2) ? B2 : B3;
            ac0 = __builtin_amdgcn_mfma_f32_16x16x32_f16(A[0][kt], B, ac0, 0, 0, 0);
            ac1 = __builtin_amdgcn_mfma_f32_16x16x32_f16(A[1][kt], B, ac1, 0, 0, 0);
            ac2 = __builtin_amdgcn_mfma_f32_16x16x32_f16(A[2][kt], B, ac2, 0, 0, 0);
            ac3 = __builtin_amdgcn_mfma_f32_16x16x32_f16(A[3][kt], B, ac3, 0, 0, 0);
        }

        // ---- in-lane gate nonlinearities + c/h update (4 cells) ----
        float h0, h1, h2, h3;
        {
            const float i0 = fast_sigmoid(ac0[0]), f0 = fast_sigmoid(ac1[0]);
            const float g0 = fast_tanh(ac2[0]),    o0 = fast_sigmoid(ac3[0]);
            c0 = __builtin_fmaf(f0, c0, i0 * g0);  h0 = o0 * fast_tanh(c0);
            const float i1 = fast_sigmoid(ac0[1]), f1 = fast_sigmoid(ac1[1]);
            const float g1 = fast_tanh(ac2[1]),    o1 = fast_sigmoid(ac3[1]);
            c1 = __builtin_fmaf(f1, c1, i1 * g1);  h1 = o1 * fast_tanh(c1);
            const float i2 = fast_sigmoid(ac0[2]), f2 = fast_sigmoid(ac1[2]);
            const float g2 = fast_tanh(ac2[2]),    o2 = fast_sigmoid(ac3[2]);
            c2 = __builtin_fmaf(f2, c2, i2 * g2);  h2 = o2 * fast_tanh(c2);
            const float i3 = fast_sigmoid(ac0[3]), f3 = fast_sigmoid(ac1[3]);
            const float g3 = fast_tanh(ac2[3]),    o3 = fast_sigmoid(ac3[3]);
            c3 = __builtin_fmaf(f3, c3, i3 * g3);  h3 = o3 * fast_tanh(c3);
        }

        // pack h pairs (k ascending): (h0,h1), (h2,h3)
        half2v hp01, hp23;
        hp01[0] = (_Float16)h0; hp01[1] = (_Float16)h1;
        hp23[0] = (_Float16)h2; hp23[1] = (_Float16)h3;

        // ---- output partial: this lane's contribution for chain n ----
        float pp = fdot2(hp23, wl23, fdot2(hp01, wl01, 0.0f));
        pp += __shfl_xor(pp, 16, 64);
        pp += __shfl_xor(pp, 32, 64);
        if (qk == 0) pout[p][n][w] = pp;      // per-wave partial for chain n

        // ---- wave 7: combine LAST step's partials -> out[s-1] ----
        if (w == 7 && l < T_CH && s > 0) {
            const f4 pa = *(const f4*)&pout[p ^ 1][l][0];
            const f4 pb = *(const f4*)&pout[p ^ 1][l][4];
            out[(s - 1) * T_CH + l] =
                pa.x + pa.y + pa.z + pa.w + pb.x + pb.y + pb.z + pb.w + blin;
        }

        // ---- write h_s to the other buffer in B-frag order ----
        // j = j0 + r (r=0..3): kt = w>>1; lane-group g = 2*(w&1) + (qk>>1);
        // elem = 4*(qk&1) + r. Data = k-ascending pairs (hp01, hp23).
        {
            const int ktw = w >> 1;
            const int lp  = (2 * (w & 1) + (qk >> 1)) * 16 + n;
            half2v* dst = (half2v*)&hfrag[p ^ 1][ktw][lp][4 * (qk & 1)];
            dst[0] = hp01;
            dst[1] = hp23;
        }

        __syncthreads();   // h_s / partials visible; buffers swap next step
    }

    // ---- drain: out[S-1] ----
    if (w == 7 && l < T_CH) {
        const int pb2 = (S_TOTAL - 1) & 1;
        const f4 pa = *(const f4*)&pout[pb2][l][0];
        const f4 pb = *(const f4*)&pout[pb2][l][4];
        out[(S_TOTAL - 1) * T_CH + l] =
            pa.x + pa.y + pa.z + pa.w + pb.x + pb.y + pb.z + pb.w + blin;
    }
}

extern "C" void kernel_launch(void* const* d_in, const int* in_sizes, int n_in,
                              void* d_out, int out_size, void* d_ws, size_t ws_size,
                              hipStream_t stream) {
    const float* x     = (const float*)d_in[0];
    const float* W_ih  = (const float*)d_in[1];
    const float* W_hh  = (const float*)d_in[2];
    const float* b_ih  = (const float*)d_in[3];
    const float* b_hh  = (const float*)d_in[4];
    const float* W_lin = (const float*)d_in[5];
    const float* b_lin = (const float*)d_in[6];
    float* out = (float*)d_out;

    hipLaunchKernelGGL(lstm_mfma, dim3(1), dim3(NT), 0, stream,
                       x, W_ih, W_hh, b_ih, b_hh, W_lin, b_lin, out);
}